// Round 1
// baseline (691.697 us; speedup 1.0000x reference)
//
#include <hip/hip_runtime.h>
#include <math.h>

#define G_GENES 2000
#define C_CELLS 128
#define H_DIM   256
#define CE_DIM  64

__device__ __forceinline__ float eluf(float x) {
    return x > 0.0f ? x : expm1f(x);
}

// ---------------------------------------------------------------------------
// K1: At[h][c] = (elu(ctrl@ce_w1+b1) @ ce_w2 + b2)[c] @ g_w1[1:65, h]
// One block per cell c. 256 threads.
// ---------------------------------------------------------------------------
__global__ __launch_bounds__(256) void k_precompute_at(
    const float* __restrict__ ctrl, const float* __restrict__ ce_w1,
    const float* __restrict__ ce_b1, const float* __restrict__ ce_w2,
    const float* __restrict__ ce_b2, const float* __restrict__ g_w1,
    float* __restrict__ At)
{
    __shared__ float crow[G_GENES];
    __shared__ float hid[H_DIM];
    __shared__ float cel[CE_DIM];
    const int c = blockIdx.x;
    const int t = threadIdx.x;

    for (int i = t; i < G_GENES; i += 256) crow[i] = ctrl[(size_t)c * G_GENES + i];
    __syncthreads();

    // hidden[t] = elu(sum_k crow[k] * ce_w1[k][t] + b1[t])
    float a0 = 0.f, a1 = 0.f, a2 = 0.f, a3 = 0.f;
    for (int k = 0; k < G_GENES; k += 4) {
        a0 = fmaf(crow[k + 0], ce_w1[(size_t)(k + 0) * H_DIM + t], a0);
        a1 = fmaf(crow[k + 1], ce_w1[(size_t)(k + 1) * H_DIM + t], a1);
        a2 = fmaf(crow[k + 2], ce_w1[(size_t)(k + 2) * H_DIM + t], a2);
        a3 = fmaf(crow[k + 3], ce_w1[(size_t)(k + 3) * H_DIM + t], a3);
    }
    hid[t] = eluf((a0 + a1) + (a2 + a3) + ce_b1[t]);
    __syncthreads();

    if (t < CE_DIM) {
        float s = ce_b2[t];
        #pragma unroll 4
        for (int h = 0; h < H_DIM; ++h) s = fmaf(hid[h], ce_w2[(size_t)h * CE_DIM + t], s);
        cel[t] = s;
    }
    __syncthreads();

    // At[t][c] = sum_e cel[e] * g_w1[1+e][t]
    float a = 0.f;
    #pragma unroll 8
    for (int e = 0; e < CE_DIM; ++e) a = fmaf(cel[e], g_w1[(size_t)(1 + e) * H_DIM + t], a);
    At[(size_t)t * C_CELLS + c] = a;
}

// ---------------------------------------------------------------------------
// K2: p_all[g][h] = (1/128) * sum_c elu(ctrl[c,g]*w1[0,h] + At[h,c] + B[g,h])
// One block per gene. 256 threads.
// ---------------------------------------------------------------------------
__global__ __launch_bounds__(256) void k_pmean(
    const float* __restrict__ ctrl, const float* __restrict__ shiftv,
    const int* __restrict__ gidx, const float* __restrict__ gtab,
    const float* __restrict__ g_w1, const float* __restrict__ g_b1,
    const float* __restrict__ At, float* __restrict__ p_all)
{
    __shared__ float cc[C_CELLS];
    __shared__ float gt[CE_DIM];
    __shared__ float Bv[H_DIM];
    __shared__ float w1r0[H_DIM];
    __shared__ __align__(16) float x1t[32 * C_CELLS];
    __shared__ float red[256];

    const int g = blockIdx.x;
    const int t = threadIdx.x;
    const int idx = gidx[g];

    if (t < C_CELLS) cc[t] = ctrl[(size_t)t * G_GENES + idx];
    else if (t < C_CELLS + CE_DIM) gt[t - C_CELLS] = gtab[(size_t)idx * CE_DIM + (t - C_CELLS)];
    __syncthreads();

    {
        const float sh = shiftv[idx];
        float b = g_b1[t] + 128.0f * g_w1[(size_t)130 * H_DIM + t] + sh * g_w1[(size_t)129 * H_DIM + t];
        #pragma unroll 8
        for (int e = 0; e < CE_DIM; ++e) b = fmaf(gt[e], g_w1[(size_t)(65 + e) * H_DIM + t], b);
        Bv[t] = b;
        w1r0[t] = g_w1[t];
    }
    __syncthreads();

    const int hh = t >> 7;       // 0..1
    const int cl = t & 127;      // cell lane
    const float ccv = cc[cl];

    for (int tile = 0; tile < 8; ++tile) {
        const int h0 = tile * 32;
        for (int hi = hh; hi < 32; hi += 2) {
            const int h = h0 + hi;
            float v = fmaf(ccv, w1r0[h], At[(size_t)h * C_CELLS + cl] + Bv[h]);
            x1t[hi * C_CELLS + cl] = eluf(v);
        }
        __syncthreads();
        {
            const int hi = t >> 3, l = t & 7;
            const float4* xr = (const float4*)&x1t[hi * C_CELLS + l * 16];
            float4 v0 = xr[0], v1 = xr[1], v2 = xr[2], v3 = xr[3];
            red[t] = ((v0.x + v0.y) + (v0.z + v0.w)) + ((v1.x + v1.y) + (v1.z + v1.w))
                   + ((v2.x + v2.y) + (v2.z + v2.w)) + ((v3.x + v3.y) + (v3.z + v3.w));
        }
        __syncthreads();
        if (t < 32) {
            float s = 0.f;
            #pragma unroll
            for (int l = 0; l < 8; ++l) s += red[t * 8 + l];
            p_all[(size_t)g * H_DIM + h0 + t] = s * (1.0f / 128.0f);
        }
        __syncthreads();
    }
}

// ---------------------------------------------------------------------------
// K3: q[g][j] = p[g,:] @ g_w2[256:512, j] + g_b2[j]   (in-place over p_all)
// One block per 32 genes. 256 threads (thread = j).
// ---------------------------------------------------------------------------
__global__ __launch_bounds__(256) void k_qall(
    const float* __restrict__ g_w2, const float* __restrict__ g_b2,
    float* __restrict__ p_all)
{
    __shared__ float pl[32 * H_DIM];
    const int g0 = blockIdx.x * 32;
    const int t = threadIdx.x;
    const int ng = min(32, G_GENES - g0);

    for (int i = t; i < ng * H_DIM; i += 256) pl[i] = p_all[(size_t)g0 * H_DIM + i];
    __syncthreads();

    float accs[32];
    #pragma unroll
    for (int gg = 0; gg < 32; ++gg) accs[gg] = g_b2[t];

    for (int h = 0; h < H_DIM; ++h) {
        const float w = g_w2[(size_t)(256 + h) * H_DIM + t];
        #pragma unroll
        for (int gg = 0; gg < 32; ++gg) accs[gg] = fmaf(pl[gg * H_DIM + h], w, accs[gg]);
    }
    for (int gg = 0; gg < ng; ++gg) p_all[(size_t)(g0 + gg) * H_DIM + t] = accs[gg];
}

// ---------------------------------------------------------------------------
// K4 (main): per gene g:
//   x1[c,h] = elu(cc[c]*w1r0[h] + At[h,c] + Bv[h])          (tile in LDS)
//   x2[c,j] = x1[c,:] @ W2a[:,j] + q[g,j]                   (register GEMM)
//   logit[c] = sum_j elu(x2[c,j]) * w3[j]                   (per-gene consts cancel)
//   out[:,g] = softmax_c(logit)
// ---------------------------------------------------------------------------
__global__ __launch_bounds__(256, 2) void k_main(
    const float* __restrict__ ctrl, const float* __restrict__ shiftv,
    const int* __restrict__ gidx, const float* __restrict__ gtab,
    const float* __restrict__ g_w1, const float* __restrict__ g_b1,
    const float* __restrict__ g_w2, const float* __restrict__ g_w3,
    const float* __restrict__ At, const float* __restrict__ q_all,
    float* __restrict__ out)
{
    __shared__ float cc[C_CELLS];
    __shared__ float gt[CE_DIM];
    __shared__ float Bv[H_DIM];
    __shared__ float w1r0[H_DIM];
    __shared__ float qv[H_DIM];
    __shared__ float w3v[H_DIM];
    __shared__ __align__(16) float x1t[32 * C_CELLS];   // 16 KB
    __shared__ __align__(16) float w2t[32 * H_DIM];     // 32 KB (reused as red2 in epilogue)
    __shared__ float ll[C_CELLS];
    __shared__ float tr[C_CELLS];

    const int g = blockIdx.x;
    const int t = threadIdx.x;
    const int idx = gidx[g];

    if (t < C_CELLS) cc[t] = ctrl[(size_t)t * G_GENES + idx];
    else if (t < C_CELLS + CE_DIM) gt[t - C_CELLS] = gtab[(size_t)idx * CE_DIM + (t - C_CELLS)];
    __syncthreads();

    {
        const float sh = shiftv[idx];
        float b = g_b1[t] + 128.0f * g_w1[(size_t)130 * H_DIM + t] + sh * g_w1[(size_t)129 * H_DIM + t];
        #pragma unroll 8
        for (int e = 0; e < CE_DIM; ++e) b = fmaf(gt[e], g_w1[(size_t)(65 + e) * H_DIM + t], b);
        Bv[t] = b;
        w1r0[t] = g_w1[t];
        qv[t] = q_all[(size_t)g * H_DIM + t];
        w3v[t] = g_w3[t];
    }
    __syncthreads();

    const int hh = t >> 7;
    const int cl = t & 127;
    const float ccv = cc[cl];

    const int cg = t & 7;        // 8 c-groups of 16
    const int jg = t >> 3;       // 32 j-groups of 8
    const int c0 = cg * 16;
    const int j0 = jg * 8;

    float acc[16][8] = {};

    for (int tile = 0; tile < 8; ++tile) {
        const int h0 = tile * 32;
        // stage W2a tile (rows h0..h0+31 of g_w2, contiguous)
        {
            const float4* src = (const float4*)(g_w2 + (size_t)h0 * H_DIM);
            float4* dst = (float4*)w2t;
            for (int i = t; i < 32 * H_DIM / 4; i += 256) dst[i] = src[i];
        }
        // compute x1 tile
        for (int hi = hh; hi < 32; hi += 2) {
            const int h = h0 + hi;
            float v = fmaf(ccv, w1r0[h], At[(size_t)h * C_CELLS + cl] + Bv[h]);
            x1t[hi * C_CELLS + cl] = eluf(v);
        }
        __syncthreads();

        // register-tiled GEMM: 16 c x 8 j per thread
        #pragma unroll 2
        for (int hi = 0; hi < 32; ++hi) {
            float4 xv0 = *(const float4*)&x1t[hi * C_CELLS + c0 + 0];
            float4 xv1 = *(const float4*)&x1t[hi * C_CELLS + c0 + 4];
            float4 xv2 = *(const float4*)&x1t[hi * C_CELLS + c0 + 8];
            float4 xv3 = *(const float4*)&x1t[hi * C_CELLS + c0 + 12];
            float4 wv0 = *(const float4*)&w2t[hi * H_DIM + j0 + 0];
            float4 wv1 = *(const float4*)&w2t[hi * H_DIM + j0 + 4];
            float xs[16] = {xv0.x, xv0.y, xv0.z, xv0.w, xv1.x, xv1.y, xv1.z, xv1.w,
                            xv2.x, xv2.y, xv2.z, xv2.w, xv3.x, xv3.y, xv3.z, xv3.w};
            float wv[8]  = {wv0.x, wv0.y, wv0.z, wv0.w, wv1.x, wv1.y, wv1.z, wv1.w};
            #pragma unroll
            for (int ci = 0; ci < 16; ++ci)
                #pragma unroll
                for (int jj = 0; jj < 8; ++jj)
                    acc[ci][jj] = fmaf(xs[ci], wv[jj], acc[ci][jj]);
        }
        __syncthreads();
    }

    // epilogue: logit partials  part[ci] = sum_jj elu(acc+q)*w3
    float part[16];
    #pragma unroll
    for (int ci = 0; ci < 16; ++ci) part[ci] = 0.f;
    #pragma unroll
    for (int jj = 0; jj < 8; ++jj) {
        const float q = qv[j0 + jj];
        const float w3 = w3v[j0 + jj];
        #pragma unroll
        for (int ci = 0; ci < 16; ++ci)
            part[ci] = fmaf(eluf(acc[ci][jj] + q), w3, part[ci]);
    }

    // reduce over 32 j-groups per cell (reuse w2t as [128][33])
    float* red2 = w2t;
    #pragma unroll
    for (int ci = 0; ci < 16; ++ci) red2[(c0 + ci) * 33 + jg] = part[ci];
    __syncthreads();

    if (t < C_CELLS) {
        float s = 0.f;
        #pragma unroll 8
        for (int j2 = 0; j2 < 32; ++j2) s += red2[t * 33 + j2];
        ll[t] = s;
        tr[t] = s;
    }
    __syncthreads();

    // max over 128 cells
    for (int s2 = 64; s2 > 0; s2 >>= 1) {
        if (t < s2) tr[t] = fmaxf(tr[t], tr[t + s2]);
        __syncthreads();
    }
    const float m = tr[0];
    __syncthreads();

    float e = 0.f;
    if (t < C_CELLS) {
        e = expf(ll[t] - m);
        tr[t] = e;
    }
    __syncthreads();
    for (int s2 = 64; s2 > 0; s2 >>= 1) {
        if (t < s2) tr[t] = tr[t] + tr[t + s2];
        __syncthreads();
    }
    const float S = tr[0];
    if (t < C_CELLS) out[(size_t)t * G_GENES + g] = e / S;
}

// ---------------------------------------------------------------------------
extern "C" void kernel_launch(void* const* d_in, const int* in_sizes, int n_in,
                              void* d_out, int out_size, void* d_ws, size_t ws_size,
                              hipStream_t stream) {
    const float* ctrl   = (const float*)d_in[0];
    const float* shiftv = (const float*)d_in[1];
    const int*   gidx   = (const int*)d_in[2];
    const float* ce_w1  = (const float*)d_in[3];
    const float* ce_b1  = (const float*)d_in[4];
    const float* ce_w2  = (const float*)d_in[5];
    const float* ce_b2  = (const float*)d_in[6];
    const float* gtab   = (const float*)d_in[7];
    const float* g_w1   = (const float*)d_in[8];
    const float* g_b1   = (const float*)d_in[9];
    const float* g_w2   = (const float*)d_in[10];
    const float* g_b2   = (const float*)d_in[11];
    const float* g_w3   = (const float*)d_in[12];
    // g_b3 (d_in[13]) and the p2@w3b term are per-gene constants: cancel in softmax.

    float* At    = (float*)d_ws;                 // 256*128 floats
    float* p_all = At + H_DIM * C_CELLS;         // 2000*256 floats (becomes q_all in-place)
    float* out   = (float*)d_out;

    k_precompute_at<<<C_CELLS, 256, 0, stream>>>(ctrl, ce_w1, ce_b1, ce_w2, ce_b2, g_w1, At);
    k_pmean<<<G_GENES, 256, 0, stream>>>(ctrl, shiftv, gidx, gtab, g_w1, g_b1, At, p_all);
    k_qall<<<(G_GENES + 31) / 32, 256, 0, stream>>>(g_w2, g_b2, p_all);
    k_main<<<G_GENES, 256, 0, stream>>>(ctrl, shiftv, gidx, gtab, g_w1, g_b1, g_w2, g_w3,
                                        At, p_all, out);
}

// Round 2
// 321.565 us; speedup vs baseline: 2.1510x; 2.1510x over previous
//
#include <hip/hip_runtime.h>
#include <math.h>

#define G_GENES 2000
#define C_CELLS 128
#define H_DIM   256
#define CE_DIM  64
#define LDA     40   // x1t row stride in bf16 elems (32 + 8 pad): conflict-free b128 r/w

typedef __attribute__((ext_vector_type(8))) short short8;
typedef __attribute__((ext_vector_type(4))) float floatx4;

__device__ __forceinline__ float eluf(float x) {
    return x > 0.0f ? x : expm1f(x);
}
__device__ __forceinline__ unsigned short f2bf(float v) {
    unsigned u = __float_as_uint(v);
    u += 0x7FFF + ((u >> 16) & 1);          // RNE
    return (unsigned short)(u >> 16);
}
__device__ __forceinline__ float bf2f(unsigned short s) {
    return __uint_as_float(((unsigned)s) << 16);
}

// ---------------------------------------------------------------------------
// K1: Atc[c][h] = (elu(ctrl@ce_w1+b1) @ ce_w2 + b2)[c] @ g_w1[1:65, h]
// One block per cell c. 256 threads (t = h).
// ---------------------------------------------------------------------------
__global__ __launch_bounds__(256) void k_precompute_at(
    const float* __restrict__ ctrl, const float* __restrict__ ce_w1,
    const float* __restrict__ ce_b1, const float* __restrict__ ce_w2,
    const float* __restrict__ ce_b2, const float* __restrict__ g_w1,
    float* __restrict__ Atc)
{
    __shared__ float crow[G_GENES];
    __shared__ float hid[H_DIM];
    __shared__ float cel[CE_DIM];
    const int c = blockIdx.x;
    const int t = threadIdx.x;

    for (int i = t; i < G_GENES; i += 256) crow[i] = ctrl[(size_t)c * G_GENES + i];
    __syncthreads();

    float a0 = 0.f, a1 = 0.f, a2 = 0.f, a3 = 0.f;
    for (int k = 0; k < G_GENES; k += 4) {
        a0 = fmaf(crow[k + 0], ce_w1[(size_t)(k + 0) * H_DIM + t], a0);
        a1 = fmaf(crow[k + 1], ce_w1[(size_t)(k + 1) * H_DIM + t], a1);
        a2 = fmaf(crow[k + 2], ce_w1[(size_t)(k + 2) * H_DIM + t], a2);
        a3 = fmaf(crow[k + 3], ce_w1[(size_t)(k + 3) * H_DIM + t], a3);
    }
    hid[t] = eluf((a0 + a1) + (a2 + a3) + ce_b1[t]);
    __syncthreads();

    if (t < CE_DIM) {
        float s = ce_b2[t];
        #pragma unroll 4
        for (int h = 0; h < H_DIM; ++h) s = fmaf(hid[h], ce_w2[(size_t)h * CE_DIM + t], s);
        cel[t] = s;
    }
    __syncthreads();

    float a = 0.f;
    #pragma unroll 8
    for (int e = 0; e < CE_DIM; ++e) a = fmaf(cel[e], g_w1[(size_t)(1 + e) * H_DIM + t], a);
    Atc[(size_t)c * H_DIM + t] = a;   // c-major: coalesced write, per-c rows for k_main
}

// ---------------------------------------------------------------------------
// K0: w2abt[n][k] = bf16(g_w2[k][n])  for k<256 (the W2a half), transposed so
// B-fragments (8 consecutive k for fixed n) are contiguous 16B global loads.
// ---------------------------------------------------------------------------
__global__ __launch_bounds__(256) void k_w2abt(
    const float* __restrict__ g_w2, unsigned short* __restrict__ w2abt)
{
    const int n = blockIdx.x;    // 0..255
    const int k = threadIdx.x;   // 0..255
    w2abt[(size_t)n * H_DIM + k] = f2bf(g_w2[(size_t)k * H_DIM + n]);
}

// ---------------------------------------------------------------------------
// K_main: one block per gene. 256 threads = 4 waves.
//  x1[c,h] = elu(cc[c]*w1r0[h] + Atc[c,h] + Bv[h])  -> bf16 LDS tile (K-tiled)
//  GEMM x1(128x256) @ W2a(256x256) via mfma_f32_16x16x32_bf16
//    wave w owns j-columns [w*64, w*64+64), all 128 rows: 8 mt x 4 nt tiles.
//  p[h] = mean_c x1[c,h] accumulated from the LDS tiles (fused k_pmean)
//  q[j] = p @ W2b[:,j] + b2[j]                       (fused k_qall, fp32)
//  logit[c] = sum_j elu(acc+q[j])*w3[j]; out[:,g] = softmax_c
// ---------------------------------------------------------------------------
__global__ __launch_bounds__(256, 2) void k_main(
    const float* __restrict__ ctrl, const float* __restrict__ shiftv,
    const int* __restrict__ gidx, const float* __restrict__ gtab,
    const float* __restrict__ g_w1, const float* __restrict__ g_b1,
    const float* __restrict__ g_w2, const float* __restrict__ g_b2,
    const float* __restrict__ g_w3, const float* __restrict__ Atc,
    const unsigned short* __restrict__ w2abt, float* __restrict__ out)
{
    __shared__ float cc[C_CELLS];
    __shared__ float gt[CE_DIM];
    __shared__ __align__(16) float Bv[H_DIM];
    __shared__ __align__(16) float w1r0[H_DIM];
    __shared__ float w3v[H_DIM];
    __shared__ float pvec[H_DIM];
    __shared__ float qv[H_DIM];
    __shared__ __align__(16) unsigned short x1t[C_CELLS * LDA];  // 10 KB
    __shared__ float pp[32 * 9];
    __shared__ float red2[C_CELLS * 5];
    __shared__ float ll[C_CELLS];
    __shared__ float tr[C_CELLS];

    const int g = blockIdx.x;
    const int t = threadIdx.x;
    const int idx = gidx[g];

    if (t < C_CELLS) cc[t] = ctrl[(size_t)t * G_GENES + idx];
    else if (t < C_CELLS + CE_DIM) gt[t - C_CELLS] = gtab[(size_t)idx * CE_DIM + (t - C_CELLS)];
    __syncthreads();

    {
        const float sh = shiftv[idx];
        float b = g_b1[t] + 128.0f * g_w1[(size_t)130 * H_DIM + t] + sh * g_w1[(size_t)129 * H_DIM + t];
        #pragma unroll 8
        for (int e = 0; e < CE_DIM; ++e) b = fmaf(gt[e], g_w1[(size_t)(65 + e) * H_DIM + t], b);
        Bv[t] = b;
        w1r0[t] = g_w1[t];
        w3v[t] = g_w3[t];
    }
    __syncthreads();

    const int c    = t & 127;      // cell this thread computes x1 for
    const int half = t >> 7;       // which pair of k-groups
    const float ccv = cc[c];
    const int lane = t & 63;
    const int w    = t >> 6;       // wave id: owns j in [w*64, w*64+64)
    const int quad = lane >> 4;
    const int nlo  = lane & 15;

    floatx4 acc[8][4];
    #pragma unroll
    for (int mt = 0; mt < 8; ++mt)
        #pragma unroll
        for (int nt = 0; nt < 4; ++nt)
            acc[mt][nt] = (floatx4){0.f, 0.f, 0.f, 0.f};

    // B-frag base: lane holds B[k=quad*8+j][n=w*64+nt*16+nlo], contiguous in k
    const unsigned short* bbase = w2abt + (size_t)(w * 64 + nlo) * H_DIM + quad * 8;

    for (int kt = 0; kt < 8; ++kt) {
        // fold previous tile's p partials (pp written in prev phase B, synced)
        if (kt && t < 32) {
            float s = 0.f;
            #pragma unroll
            for (int gg = 0; gg < 8; ++gg) s += pp[t * 9 + gg];
            pvec[(kt - 1) * 32 + t] = s * (1.0f / 128.0f);
        }
        // compute x1 tile (bf16): thread does 2 groups of 8 h for its cell c
        #pragma unroll
        for (int ii = 0; ii < 2; ++ii) {
            const int kgrp = half * 2 + ii;
            const int h0 = kt * 32 + kgrp * 8;
            float4 at0 = *(const float4*)(Atc + (size_t)c * H_DIM + h0);
            float4 at1 = *(const float4*)(Atc + (size_t)c * H_DIM + h0 + 4);
            float4 bv0 = *(const float4*)(Bv + h0);
            float4 bv1 = *(const float4*)(Bv + h0 + 4);
            float4 wr0 = *(const float4*)(w1r0 + h0);
            float4 wr1 = *(const float4*)(w1r0 + h0 + 4);
            float v0 = eluf(fmaf(ccv, wr0.x, at0.x + bv0.x));
            float v1 = eluf(fmaf(ccv, wr0.y, at0.y + bv0.y));
            float v2 = eluf(fmaf(ccv, wr0.z, at0.z + bv0.z));
            float v3 = eluf(fmaf(ccv, wr0.w, at0.w + bv0.w));
            float v4 = eluf(fmaf(ccv, wr1.x, at1.x + bv1.x));
            float v5 = eluf(fmaf(ccv, wr1.y, at1.y + bv1.y));
            float v6 = eluf(fmaf(ccv, wr1.z, at1.z + bv1.z));
            float v7 = eluf(fmaf(ccv, wr1.w, at1.w + bv1.w));
            uint4 pk;
            pk.x = (unsigned)f2bf(v0) | ((unsigned)f2bf(v1) << 16);
            pk.y = (unsigned)f2bf(v2) | ((unsigned)f2bf(v3) << 16);
            pk.z = (unsigned)f2bf(v4) | ((unsigned)f2bf(v5) << 16);
            pk.w = (unsigned)f2bf(v6) | ((unsigned)f2bf(v7) << 16);
            *(uint4*)&x1t[c * LDA + kgrp * 8] = pk;
        }
        __syncthreads();

        // A-fragments from LDS: lane holds x1[mt*16+nlo][kt*32 + quad*8 + j]
        short8 af[8];
        #pragma unroll
        for (int mt = 0; mt < 8; ++mt)
            af[mt] = *(const short8*)&x1t[(mt * 16 + nlo) * LDA + quad * 8];

        // B-fragments direct from global (L2-resident) + MFMA
        #pragma unroll
        for (int nt = 0; nt < 4; ++nt) {
            short8 bf = *(const short8*)(bbase + (size_t)nt * 16 * H_DIM + kt * 32);
            #pragma unroll
            for (int mt = 0; mt < 8; ++mt)
                acc[mt][nt] = __builtin_amdgcn_mfma_f32_16x16x32_bf16(af[mt], bf, acc[mt][nt], 0, 0, 0);
        }

        // p partial: column sums of the x1 tile (kk = t&31, 8 c-groups of 16)
        {
            const int kk = t & 31, grp = t >> 5;
            float s = 0.f;
            #pragma unroll
            for (int ci = 0; ci < 16; ++ci)
                s += bf2f(x1t[(grp * 16 + ci) * LDA + kk]);
            pp[kk * 9 + grp] = s;
        }
        __syncthreads();
    }
    if (t < 32) {
        float s = 0.f;
        #pragma unroll
        for (int gg = 0; gg < 8; ++gg) s += pp[t * 9 + gg];
        pvec[224 + t] = s * (1.0f / 128.0f);
    }
    __syncthreads();

    // q[j] = p @ W2b[:,j] + b2[j]  (fp32, W2b = g_w2 rows 256..511, coalesced)
    {
        float q = g_b2[t];
        const float* w2b = g_w2 + (size_t)H_DIM * H_DIM + t;
        #pragma unroll 8
        for (int h = 0; h < H_DIM; ++h) q = fmaf(pvec[h], w2b[(size_t)h * H_DIM], q);
        qv[t] = q;
    }
    __syncthreads();

    // epilogue: logit partials from MFMA acc (C/D: col=lane&15, row=quad*4+reg)
    float qj[4], w3j[4];
    #pragma unroll
    for (int nt = 0; nt < 4; ++nt) {
        const int j = w * 64 + nt * 16 + nlo;
        qj[nt] = qv[j];
        w3j[nt] = w3v[j];
    }
    #pragma unroll
    for (int mt = 0; mt < 8; ++mt) {
        #pragma unroll
        for (int reg = 0; reg < 4; ++reg) {
            float part = 0.f;
            #pragma unroll
            for (int nt = 0; nt < 4; ++nt)
                part = fmaf(eluf(acc[mt][nt][reg] + qj[nt]), w3j[nt], part);
            part += __shfl_xor(part, 1, 16);
            part += __shfl_xor(part, 2, 16);
            part += __shfl_xor(part, 4, 16);
            part += __shfl_xor(part, 8, 16);
            if (nlo == 0) red2[(mt * 16 + quad * 4 + reg) * 5 + w] = part;
        }
    }
    __syncthreads();

    if (t < C_CELLS) {
        float s = red2[t * 5 + 0] + red2[t * 5 + 1] + red2[t * 5 + 2] + red2[t * 5 + 3];
        ll[t] = s;
        tr[t] = s;
    }
    __syncthreads();

    for (int s2 = 64; s2 > 0; s2 >>= 1) {
        if (t < s2) tr[t] = fmaxf(tr[t], tr[t + s2]);
        __syncthreads();
    }
    const float m = tr[0];
    __syncthreads();

    float e = 0.f;
    if (t < C_CELLS) {
        e = expf(ll[t] - m);
        tr[t] = e;
    }
    __syncthreads();
    for (int s2 = 64; s2 > 0; s2 >>= 1) {
        if (t < s2) tr[t] = tr[t] + tr[t + s2];
        __syncthreads();
    }
    const float S = tr[0];
    if (t < C_CELLS) out[(size_t)t * G_GENES + g] = e / S;
}

// ---------------------------------------------------------------------------
extern "C" void kernel_launch(void* const* d_in, const int* in_sizes, int n_in,
                              void* d_out, int out_size, void* d_ws, size_t ws_size,
                              hipStream_t stream) {
    const float* ctrl   = (const float*)d_in[0];
    const float* shiftv = (const float*)d_in[1];
    const int*   gidx   = (const int*)d_in[2];
    const float* ce_w1  = (const float*)d_in[3];
    const float* ce_b1  = (const float*)d_in[4];
    const float* ce_w2  = (const float*)d_in[5];
    const float* ce_b2  = (const float*)d_in[6];
    const float* gtab   = (const float*)d_in[7];
    const float* g_w1   = (const float*)d_in[8];
    const float* g_b1   = (const float*)d_in[9];
    const float* g_w2   = (const float*)d_in[10];
    const float* g_b2   = (const float*)d_in[11];
    const float* g_w3   = (const float*)d_in[12];
    // g_b3 and the p2@w3b term are per-gene constants: cancel in softmax.

    float* Atc = (float*)d_ws;                               // 128*256 f32
    unsigned short* w2abt = (unsigned short*)(Atc + C_CELLS * H_DIM);  // 256*256 bf16
    float* out = (float*)d_out;

    k_precompute_at<<<C_CELLS, 256, 0, stream>>>(ctrl, ce_w1, ce_b1, ce_w2, ce_b2, g_w1, Atc);
    k_w2abt<<<H_DIM, 256, 0, stream>>>(g_w2, w2abt);
    k_main<<<G_GENES, 256, 0, stream>>>(ctrl, shiftv, gidx, gtab, g_w1, g_b1, g_w2, g_b2,
                                        g_w3, Atc, w2abt, out);
}

// Round 3
// 238.956 us; speedup vs baseline: 2.8947x; 1.3457x over previous
//
#include <hip/hip_runtime.h>
#include <math.h>

#define G_GENES 2000
#define C_CELLS 128
#define H_DIM   256
#define CE_DIM  64
#define LDAe    264   // x1t row stride in bf16 elems (256 + 8 pad); 528 B = 33*16 OK

typedef __attribute__((ext_vector_type(8))) short short8;
typedef __attribute__((ext_vector_type(4))) float floatx4;

__device__ __forceinline__ float eluf(float x) {
    float e = __expf(x) - 1.0f;          // |err| ~1e-7 abs for x<=0, fine vs bf16 noise
    return x > 0.0f ? x : e;
}
__device__ __forceinline__ unsigned short f2bf(float v) {
    unsigned u = __float_as_uint(v);
    u += 0x7FFF + ((u >> 16) & 1);       // RNE
    return (unsigned short)(u >> 16);
}
__device__ __forceinline__ float bf2f(unsigned short s) {
    return __uint_as_float(((unsigned)s) << 16);
}

// ---------------------------------------------------------------------------
// K1a: split-K partials of hid_pre[c][h] = ctrl[c,:] @ ce_w1[:,h]
// grid = 128 cells * 8 k-chunks (250 k each), 256 threads (t = h).
// ---------------------------------------------------------------------------
__global__ __launch_bounds__(256) void k1a(
    const float* __restrict__ ctrl, const float* __restrict__ ce_w1,
    float* __restrict__ hidpart)
{
    __shared__ float crow[250];
    const int c  = blockIdx.x >> 3;
    const int kc = blockIdx.x & 7;
    const int t  = threadIdx.x;

    if (t < 250) crow[t] = ctrl[(size_t)c * G_GENES + kc * 250 + t];
    __syncthreads();

    float s0 = 0.f, s1 = 0.f;
    const float* w = ce_w1 + (size_t)(kc * 250) * H_DIM + t;
    #pragma unroll 5
    for (int k = 0; k < 250; k += 2) {
        s0 = fmaf(crow[k], w[(size_t)k * H_DIM], s0);
        s1 = fmaf(crow[k + 1], w[(size_t)(k + 1) * H_DIM], s1);
    }
    hidpart[((size_t)c * 8 + kc) * H_DIM + t] = s0 + s1;
}

// ---------------------------------------------------------------------------
// K1b: hid = elu(sum parts + b1); cel = hid@ce_w2 + b2; Atc[c][h] = cel@g_w1[1:65]
// grid = 128 cells, 256 threads.
// ---------------------------------------------------------------------------
__global__ __launch_bounds__(256) void k1b(
    const float* __restrict__ hidpart, const float* __restrict__ ce_b1,
    const float* __restrict__ ce_w2, const float* __restrict__ ce_b2,
    const float* __restrict__ g_w1, float* __restrict__ Atc)
{
    __shared__ float hid[H_DIM];
    __shared__ float cel[CE_DIM];
    const int c = blockIdx.x;
    const int t = threadIdx.x;

    float s = ce_b1[t];
    #pragma unroll
    for (int p = 0; p < 8; ++p) s += hidpart[((size_t)c * 8 + p) * H_DIM + t];
    hid[t] = eluf(s);
    __syncthreads();

    if (t < CE_DIM) {
        float q = ce_b2[t];
        #pragma unroll 8
        for (int h = 0; h < H_DIM; ++h) q = fmaf(hid[h], ce_w2[(size_t)h * CE_DIM + t], q);
        cel[t] = q;
    }
    __syncthreads();

    float a = 0.f;
    #pragma unroll 8
    for (int e = 0; e < CE_DIM; ++e) a = fmaf(cel[e], g_w1[(size_t)(1 + e) * H_DIM + t], a);
    Atc[(size_t)c * H_DIM + t] = a;
}

// ---------------------------------------------------------------------------
// K0: w2abt[n][k] = bf16(g_w2[k][n]) for k<256 (W2a half, transposed)
// ---------------------------------------------------------------------------
__global__ __launch_bounds__(256) void k_w2abt(
    const float* __restrict__ g_w2, unsigned short* __restrict__ w2abt)
{
    const int n = blockIdx.x;
    const int k = threadIdx.x;
    w2abt[(size_t)n * H_DIM + k] = f2bf(g_w2[(size_t)k * H_DIM + n]);
}

// ---------------------------------------------------------------------------
// K_main: one block per gene, 512 threads = 8 waves (2m x 4n wave grid).
// ---------------------------------------------------------------------------
__global__ __launch_bounds__(512, 4) void k_main(
    const float* __restrict__ ctrl, const float* __restrict__ shiftv,
    const int* __restrict__ gidx, const float* __restrict__ gtab,
    const float* __restrict__ g_w1, const float* __restrict__ g_b1,
    const float* __restrict__ g_w2, const float* __restrict__ g_b2,
    const float* __restrict__ g_w3, const float* __restrict__ Atc,
    const unsigned short* __restrict__ w2abt, float* __restrict__ out)
{
    __shared__ __align__(16) unsigned short x1t[C_CELLS * LDAe];  // 67584 B
    __shared__ float cc[C_CELLS];
    __shared__ float gt[CE_DIM];
    __shared__ __align__(16) float Bv[H_DIM];
    __shared__ __align__(16) float w1r0[H_DIM];
    __shared__ float w3v[H_DIM];
    __shared__ float pvec[H_DIM];
    __shared__ float qv[H_DIM];
    __shared__ float red2[C_CELLS * 5];
    __shared__ float wred[4];

    const int g = blockIdx.x;
    const int t = threadIdx.x;
    const int idx = gidx[g];

    if (t < C_CELLS) cc[t] = ctrl[(size_t)t * G_GENES + idx];
    else if (t < C_CELLS + CE_DIM) gt[t - C_CELLS] = gtab[(size_t)idx * CE_DIM + (t - C_CELLS)];
    __syncthreads();

    if (t < H_DIM) {
        const float sh = shiftv[idx];
        float b = g_b1[t] + 128.0f * g_w1[(size_t)130 * H_DIM + t] + sh * g_w1[(size_t)129 * H_DIM + t];
        #pragma unroll 8
        for (int e = 0; e < CE_DIM; ++e) b = fmaf(gt[e], g_w1[(size_t)(65 + e) * H_DIM + t], b);
        Bv[t] = b;
        w1r0[t] = g_w1[t];
        w3v[t] = g_w3[t];
    }
    __syncthreads();

    // ---- x1 compute: thread = (cell = t>>2, h-quarter = t&3), 64 h each ----
    {
        const int xc = t >> 2;
        const int xh = (t & 3) * 64;
        const float ccv = cc[xc];
        #pragma unroll
        for (int i = 0; i < 8; ++i) {
            const int h0 = xh + i * 8;
            float4 at0 = *(const float4*)(Atc + (size_t)xc * H_DIM + h0);
            float4 at1 = *(const float4*)(Atc + (size_t)xc * H_DIM + h0 + 4);
            float4 bv0 = *(const float4*)(Bv + h0);
            float4 bv1 = *(const float4*)(Bv + h0 + 4);
            float4 wr0 = *(const float4*)(w1r0 + h0);
            float4 wr1 = *(const float4*)(w1r0 + h0 + 4);
            float v0 = eluf(fmaf(ccv, wr0.x, at0.x + bv0.x));
            float v1 = eluf(fmaf(ccv, wr0.y, at0.y + bv0.y));
            float v2 = eluf(fmaf(ccv, wr0.z, at0.z + bv0.z));
            float v3 = eluf(fmaf(ccv, wr0.w, at0.w + bv0.w));
            float v4 = eluf(fmaf(ccv, wr1.x, at1.x + bv1.x));
            float v5 = eluf(fmaf(ccv, wr1.y, at1.y + bv1.y));
            float v6 = eluf(fmaf(ccv, wr1.z, at1.z + bv1.z));
            float v7 = eluf(fmaf(ccv, wr1.w, at1.w + bv1.w));
            uint4 pk;
            pk.x = (unsigned)f2bf(v0) | ((unsigned)f2bf(v1) << 16);
            pk.y = (unsigned)f2bf(v2) | ((unsigned)f2bf(v3) << 16);
            pk.z = (unsigned)f2bf(v4) | ((unsigned)f2bf(v5) << 16);
            pk.w = (unsigned)f2bf(v6) | ((unsigned)f2bf(v7) << 16);
            *(uint4*)&x1t[xc * LDAe + h0] = pk;
        }
    }
    __syncthreads();   // B1: x1t complete

    const int lane = t & 63;
    const int w    = t >> 6;
    const int quad = lane >> 4;
    const int nlo  = lane & 15;
    const int wm   = w >> 2;      // 0..1 : rows [wm*64, +64)
    const int wn   = w & 3;       // 0..3 : cols [wn*64, +64)

    // ---- p[h] = mean_c x1[c,h] : wave w covers h in [w*32, w*32+32) ----
    {
        const int hh = w * 32 + (lane & 31);
        const int c0 = (lane >> 5) * 64;
        float s = 0.f;
        #pragma unroll 8
        for (int i = 0; i < 64; ++i) s += bf2f(x1t[(c0 + i) * LDAe + hh]);
        s += __shfl_xor(s, 32);
        if ((lane & 32) == 0) pvec[hh] = s * (1.0f / 128.0f);
    }
    __syncthreads();   // B2: pvec complete

    // ---- q (waves 0-3 only; waves 4-7 proceed straight to MFMA) ----
    if (t < H_DIM) {
        float q = g_b2[t];
        const float* w2b = g_w2 + (size_t)H_DIM * H_DIM + t;
        #pragma unroll 8
        for (int h = 0; h < H_DIM; ++h) q = fmaf(pvec[h], w2b[(size_t)h * H_DIM], q);
        qv[t] = q;
    }

    // ---- MFMA: 4 mt x 4 nt tiles, K=256 in 8 steps ----
    floatx4 acc[4][4];
    #pragma unroll
    for (int mt = 0; mt < 4; ++mt)
        #pragma unroll
        for (int nt = 0; nt < 4; ++nt)
            acc[mt][nt] = (floatx4){0.f, 0.f, 0.f, 0.f};

    const unsigned short* bbase = w2abt + (size_t)(wn * 64 + nlo) * H_DIM + quad * 8;
    const unsigned short* abase = &x1t[(wm * 64 + nlo) * LDAe + quad * 8];

    for (int kt = 0; kt < 8; ++kt) {
        short8 af[4];
        #pragma unroll
        for (int mt = 0; mt < 4; ++mt)
            af[mt] = *(const short8*)(abase + mt * 16 * LDAe + kt * 32);
        #pragma unroll
        for (int nt = 0; nt < 4; ++nt) {
            short8 bf = *(const short8*)(bbase + (size_t)nt * 16 * H_DIM + kt * 32);
            #pragma unroll
            for (int mt = 0; mt < 4; ++mt)
                acc[mt][nt] = __builtin_amdgcn_mfma_f32_16x16x32_bf16(af[mt], bf, acc[mt][nt], 0, 0, 0);
        }
    }
    __syncthreads();   // B3: qv complete (and x1t no longer needed)

    // ---- epilogue: logit partials (C/D: col=lane&15, row=quad*4+reg) ----
    float qj[4], w3j[4];
    #pragma unroll
    for (int nt = 0; nt < 4; ++nt) {
        const int j = wn * 64 + nt * 16 + nlo;
        qj[nt] = qv[j];
        w3j[nt] = w3v[j];
    }
    #pragma unroll
    for (int mt = 0; mt < 4; ++mt) {
        #pragma unroll
        for (int reg = 0; reg < 4; ++reg) {
            float part = 0.f;
            #pragma unroll
            for (int nt = 0; nt < 4; ++nt)
                part = fmaf(eluf(acc[mt][nt][reg] + qj[nt]), w3j[nt], part);
            part += __shfl_xor(part, 1);
            part += __shfl_xor(part, 2);
            part += __shfl_xor(part, 4);
            part += __shfl_xor(part, 8);
            if (nlo == 0)
                red2[(wm * 64 + mt * 16 + quad * 4 + reg) * 5 + wn] = part;
        }
    }
    __syncthreads();   // B4: red2 complete

    // ---- softmax over 128 cells (waves 0-1, shuffle-based) ----
    float s = 0.f, e = 0.f;
    if (t < C_CELLS) {
        s = red2[t * 5 + 0] + red2[t * 5 + 1] + red2[t * 5 + 2] + red2[t * 5 + 3];
        float m = s;
        #pragma unroll
        for (int off = 1; off < 64; off <<= 1) m = fmaxf(m, __shfl_xor(m, off));
        if (lane == 0) wred[w] = m;
    }
    __syncthreads();
    if (t < C_CELLS) {
        const float m = fmaxf(wred[0], wred[1]);
        e = __expf(s - m);
        float S = e;
        #pragma unroll
        for (int off = 1; off < 64; off <<= 1) S += __shfl_xor(S, off);
        if (lane == 0) wred[2 + w] = S;
    }
    __syncthreads();
    if (t < C_CELLS) out[(size_t)t * G_GENES + g] = e / (wred[2] + wred[3]);
}

// ---------------------------------------------------------------------------
extern "C" void kernel_launch(void* const* d_in, const int* in_sizes, int n_in,
                              void* d_out, int out_size, void* d_ws, size_t ws_size,
                              hipStream_t stream) {
    const float* ctrl   = (const float*)d_in[0];
    const float* shiftv = (const float*)d_in[1];
    const int*   gidx   = (const int*)d_in[2];
    const float* ce_w1  = (const float*)d_in[3];
    const float* ce_b1  = (const float*)d_in[4];
    const float* ce_w2  = (const float*)d_in[5];
    const float* ce_b2  = (const float*)d_in[6];
    const float* gtab   = (const float*)d_in[7];
    const float* g_w1   = (const float*)d_in[8];
    const float* g_b1   = (const float*)d_in[9];
    const float* g_w2   = (const float*)d_in[10];
    const float* g_b2   = (const float*)d_in[11];
    const float* g_w3   = (const float*)d_in[12];
    // g_b3 and the p2@w3b term are per-gene constants: cancel in softmax.

    float* Atc = (float*)d_ws;                                       // 128*256 f32
    unsigned short* w2abt = (unsigned short*)(Atc + C_CELLS * H_DIM); // 256*256 bf16
    float* hidpart = (float*)(w2abt + H_DIM * H_DIM);                 // 128*8*256 f32
    float* out = (float*)d_out;

    k1a<<<C_CELLS * 8, 256, 0, stream>>>(ctrl, ce_w1, hidpart);
    k_w2abt<<<H_DIM, 256, 0, stream>>>(g_w2, w2abt);
    k1b<<<C_CELLS, 256, 0, stream>>>(hidpart, ce_b1, ce_w2, ce_b2, g_w1, Atc);
    k_main<<<G_GENES, 512, 0, stream>>>(ctrl, shiftv, gidx, gtab, g_w1, g_b1, g_w2, g_b2,
                                        g_w3, Atc, w2abt, out);
}